// Round 9
// baseline (132.462 us; speedup 1.0000x reference)
//
#include <hip/hip_runtime.h>
#include <hip/hip_bf16.h>
#include <hip/hip_cooperative_groups.h>

namespace cg = cooperative_groups;

typedef _Float16 half8 __attribute__((ext_vector_type(8)));
typedef _Float16 half4v __attribute__((ext_vector_type(4)));
typedef float f32x4 __attribute__((ext_vector_type(4)));

#define NCOLS 176               // 48 (padded 36-group) + 128
#define TILE_ELEMS (NCOLS*32)   // 5632 f16 per K-step tile
#define TILE_U16 (TILE_ELEMS/8) // 704 uint4 units
#define WTSTR 40                // pack LDS pad
#define XSTR2 2312              // f16 per X row: 2304 + 8 pad
#define BM 16

// ---- LDS layout (bytes) ----
// GEMM phase: X @0 = 16*2312*2 = 73984 (rows 0..15 cover bytes 0..73983)
// Pack scratch T: @73984 (14080 B) -- DISJOINT from X (R8 bug: T aliased X
// rows 11-14 while both were live -> corrupted 72 blocks' inputs).
// Tail phase (aliases X region only after X is dead):
#define OFF_A36 0        // [16][40] f32  = 2560
#define OFF_TQ  2560     // [16][128] f32 = 8192
#define OFF_TPN 10752    // [16][128] f32 = 8192
#define OFF_WV  18944    // [16] f32 pad64
#define OFF_X1  19008    // [16][132] f32 = 8448
#define OFF_W2  27456    // [128][64] f16 = 16384
#define OFF_X2  43840    // [16][68] f32  = 4352
#define OFF_W3  48192    // [64][24] f16  = 3072
#define OFF_X3  51264    // [16][28] f32  = 1792 -> 53056
#define OFF_SCR 53056    // K reduce scratch (post-X-death): 24576 -> 77632
#define OFF_T   73984    // pack scratch (pre-sync; disjoint from live X)
#define SM_BYTES 88064

struct Params {
  const float *qid, *node, *leaf;
  const int *pos_idx, *neg_idx, *p_leaf, *n_leaf;
  const float *W00, *W1;
  const float *b00, *a00, *W01, *b01;
  const float *b1, *a1, *g1, *be1, *m1, *v1;
  const float *W2, *b2, *a2, *g2, *be2, *m2, *v2;
  const float *W3, *b3, *a3, *g3, *be3, *m3, *v3;
  const float *W4, *b4;
  _Float16 *Wp;          // ws: 72*5632*2 = 811008 B
  float *out;
};

// Single cooperative kernel, 256 blocks x 512 threads.
// Phase A: all blocks stage X (q|pos|neg -> f16 LDS); blocks 0..71 also pack
// their Wp tile into T (disjoint LDS) overlapped with the gather.
// threadfence + grid.sync publishes Wp device-wide.
// Phase C: barrier-free K-loop (W global->reg 4-deep, A from LDS), kg-parity
// reduction, fused MLP tail (R4-verified numerics).
__global__ __launch_bounds__(512) void fused(Params p) {
  __shared__ __align__(16) char sm[SM_BYTES];

  _Float16* X   = (_Float16*)sm;
  float*    A36 = (float*)(sm + OFF_A36);
  float*    Tq  = (float*)(sm + OFF_TQ);
  float*    Tpn = (float*)(sm + OFF_TPN);
  float*    wv  = (float*)(sm + OFF_WV);
  float*    x1  = (float*)(sm + OFF_X1);
  _Float16* W2h = (_Float16*)(sm + OFF_W2);
  float*    x2  = (float*)(sm + OFF_X2);
  _Float16* W3h = (_Float16*)(sm + OFF_W3);
  float*    x3  = (float*)(sm + OFF_X3);
  float*    scr = (float*)(sm + OFF_SCR);
  _Float16* T   = (_Float16*)(sm + OFF_T);     // pack scratch, disjoint from X

  const int tid  = threadIdx.x;
  const int wid  = tid >> 6;
  const int lane = tid & 63;
  const int lm   = lane & 15;
  const int hk   = lane >> 4;
  const int nw   = wid & 3;
  const int kg   = wid >> 2;              // 0/1 K parity
  const int m0   = blockIdx.x * BM;
  const bool HAS2 = (nw < 3);

  // ---- Phase A: X staging (all blocks) + Wp pack (blocks 0..71) ----
  auto rowbase = [&](int s, int i) -> const float* {
    if (s == 0) return p.qid + (size_t)(m0 + i) * 768;
    int idx = (s == 1 ? p.pos_idx : p.neg_idx)[m0 + i];
    int lf  = (s == 1 ? p.p_leaf  : p.n_leaf )[m0 + i];
    return ((lf == 1) ? p.leaf : p.node) + (size_t)idx * 768;
  };
  float4 sA[6], sB[6];
  auto stageLoad = [&](int s, float4* sr) {
#pragma unroll
    for (int jj = 0; jj < 6; ++jj) {
      int v = tid + jj * 512;             // < 3072 = 16 rows * 192 float4
      int i = v / 192, c4 = v - i * 192;
      sr[jj] = ((const float4*)rowbase(s, i))[c4];
    }
  };
  auto stageWrite = [&](int s, const float4* sr) {
#pragma unroll
    for (int jj = 0; jj < 6; ++jj) {
      int v = tid + jj * 512;
      int i = v / 192, c4 = v - i * 192;
      float4 f = sr[jj];
      half4v h = { (_Float16)f.x, (_Float16)f.y, (_Float16)f.z, (_Float16)f.w };
      *(half4v*)(X + i * XSTR2 + s * 768 + c4 * 4) = h;
    }
  };

  stageLoad(0, sA);
  stageLoad(1, sB);
  stageWrite(0, sA);                       // waits sA (counted vmcnt)
  stageLoad(2, sA);
  stageWrite(1, sB);
  stageWrite(2, sA);

  if (blockIdx.x < 72) {                   // pack tile g = blockIdx.x
    int g = blockIdx.x;
    int s = g / 24, t = g - s * 24;
    int k0 = t * 32;
    int w1row0 = (s == 0) ? 1536 : (s == 1 ? 0 : 768);
    for (int u = tid; u < 1024; u += 512) {          // W1 part
      int kk = u >> 5, c4 = u & 31;
      float4 f = *(const float4*)(p.W1 + (size_t)(w1row0 + k0 + kk) * 128 + c4 * 4);
      int c = 48 + c4 * 4;
      T[(c + 0) * WTSTR + kk] = (_Float16)f.x; T[(c + 1) * WTSTR + kk] = (_Float16)f.y;
      T[(c + 2) * WTSTR + kk] = (_Float16)f.z; T[(c + 3) * WTSTR + kk] = (_Float16)f.w;
    }
    for (int u = tid; u < 1152; u += 512) {          // W00 part
      int kk = u / 36, c = u - kk * 36;
      T[c * WTSTR + kk] = (_Float16)p.W00[(size_t)(s * 768 + k0 + kk) * 36 + c];
    }
    for (int u = tid; u < 384; u += 512) {           // zero pad cols 36..47
      int kk = u & 31, c = 36 + (u >> 5);
      T[c * WTSTR + kk] = (_Float16)0.f;
    }
    __syncthreads();
    uint4* dst = (uint4*)(p.Wp + (size_t)g * TILE_ELEMS);
    for (int u = tid; u < TILE_U16; u += 512) {
      int c = u >> 2, q = u & 3;
      dst[u] = *(const uint4*)&T[c * WTSTR + q * 8];
    }
  }
  __threadfence();                         // publish Wp device-wide (L2 wb)
  __syncthreads();                         // X visible block-locally
  cg::this_grid().sync();                  // Wp visible grid-wide

  // ---- Phase C: barrier-free K-loop ----
  const uint4* Wp4 = (const uint4*)p.Wp;
  const int woff = ((nw * 48 + lm) << 2) + hk;

  uint4 P[4][3];
  auto ldWp = [&](int t) {                 // tile g = kg + 2t
    const uint4* b = Wp4 + (size_t)(kg + 2 * t) * TILE_U16 + woff;
    P[t & 3][0] = b[0]; P[t & 3][1] = b[64];
    if (HAS2) P[t & 3][2] = b[128];
  };
  auto ldA = [&](int t) -> half8 {
    return *(const half8*)(X + lm * XSTR2 + (kg + 2 * t) * 32 + hk * 8);
  };

  f32x4 accA[3] = {{0.f,0.f,0.f,0.f},{0.f,0.f,0.f,0.f},{0.f,0.f,0.f,0.f}};
  f32x4 accB[3] = {{0.f,0.f,0.f,0.f},{0.f,0.f,0.f,0.f},{0.f,0.f,0.f,0.f}};
  half8 av[3];

  ldWp(0); ldWp(1); ldWp(2); ldWp(3);
  av[0] = ldA(0); av[1] = ldA(1); av[2] = ldA(2);

#pragma unroll
  for (int t = 0; t < 36; ++t) {
    half8 a  = av[t % 3];
    half8 b0 = __builtin_bit_cast(half8, P[t & 3][0]);
    half8 b1 = __builtin_bit_cast(half8, P[t & 3][1]);
    half8 b2 = __builtin_bit_cast(half8, P[t & 3][2]);
    if ((nw == 0) || (t < 12)) {
      accA[0] = __builtin_amdgcn_mfma_f32_16x16x32_f16(a, b0, accA[0], 0, 0, 0);
      accA[1] = __builtin_amdgcn_mfma_f32_16x16x32_f16(a, b1, accA[1], 0, 0, 0);
      if (HAS2) accA[2] = __builtin_amdgcn_mfma_f32_16x16x32_f16(a, b2, accA[2], 0, 0, 0);
    } else {
      accB[0] = __builtin_amdgcn_mfma_f32_16x16x32_f16(a, b0, accB[0], 0, 0, 0);
      accB[1] = __builtin_amdgcn_mfma_f32_16x16x32_f16(a, b1, accB[1], 0, 0, 0);
      if (HAS2) accB[2] = __builtin_amdgcn_mfma_f32_16x16x32_f16(a, b2, accB[2], 0, 0, 0);
    }
    if (t + 4 < 36) ldWp(t + 4);
    if (t + 3 < 36) av[t % 3] = ldA(t + 3);
  }

  // issue tail W2 loads (land during reduction)
  float4 w2r[4];
#pragma unroll
  for (int jj = 0; jj < 4; ++jj) w2r[jj] = ((const float4*)p.W2)[tid + jj * 512];

  // ---- kg-parity reduction (scr region: X dead after this barrier) ----
  __syncthreads();
  if (kg == 1) {
#pragma unroll
    for (int n = 0; n < 3; ++n) {
      if (n < 2 || HAS2) {
#pragma unroll
        for (int r = 0; r < 4; ++r) {
          int base = ((nw * 3 + n) * 2) * 256 + (hk * 4 + r) * 16 + lm;
          scr[base]       = accA[n][r];
          scr[base + 256] = accB[n][r];
        }
      }
    }
  }
  __syncthreads();
  if (kg == 0) {
#pragma unroll
    for (int n = 0; n < 3; ++n) {
      if (n < 2 || HAS2) {
#pragma unroll
        for (int r = 0; r < 4; ++r) {
          int base = ((nw * 3 + n) * 2) * 256 + (hk * 4 + r) * 16 + lm;
          float va = accA[n][r] + scr[base];
          float vb = accB[n][r] + scr[base + 256];
          int row = hk * 4 + r;
          int col = nw * 48 + n * 16 + lm;
          if (nw == 0) { if (col < 36) A36[row * 40 + col] = va; }
          else { int rc = col - 48; Tq[row * 128 + rc] = va; Tpn[row * 128 + rc] = vb; }
        }
      }
    }
  }
  __syncthreads();

  // ---- fused tail (R4-verified) ----
#pragma unroll
  for (int jj = 0; jj < 4; ++jj) {
    int u = tid + jj * 512;                // 2048 float4 = 128*64/4
    float4 f = w2r[jj];
    half4v h = { (_Float16)f.x, (_Float16)f.y, (_Float16)f.z, (_Float16)f.w };
    *(half4v*)(W2h + (u >> 4) * 64 + (u & 15) * 4) = h;
  }
  if (tid < BM) {
    float acc = p.b01[0];
    for (int c = 0; c < 36; ++c) {
      float h = A36[tid * 40 + c] + p.b00[c];
      h = (h > 0.f) ? h : p.a00[c] * h;
      acc += h * p.W01[c];
    }
    wv[tid] = acc;
  }
  __syncthreads();

#pragma unroll
  for (int j = 0; j < 4; ++j) {
    int u = tid + j * 512;                 // 2048 = 16*128
    int i = u >> 7, c = u & 127;
    float v = wv[i] * Tpn[i * 128 + c] + Tq[i * 128 + c] + p.b1[c];
    v = (v > 0.f) ? v : p.a1[c] * v;
    v = (v - p.m1[c]) * (1.f / sqrtf(p.v1[c] + 1e-3f)) * p.g1[c] + p.be1[c];
    x1[i * 132 + c] = v;
  }
  __syncthreads();

  if (tid < 256) {
    int i = tid & 15, cq = tid >> 4;
    const float* xr = x1 + i * 132;
    f32x4 acc0 = { p.b2[cq*4+0], p.b2[cq*4+1], p.b2[cq*4+2], p.b2[cq*4+3] };
    f32x4 acc1 = { 0.f, 0.f, 0.f, 0.f };
#pragma unroll 8
    for (int k = 0; k < 128; k += 2) {
      half4v w0 = *(const half4v*)(W2h + k * 64 + cq * 4);
      half4v w1 = *(const half4v*)(W2h + (k + 1) * 64 + cq * 4);
      acc0 += xr[k]     * __builtin_convertvector(w0, f32x4);
      acc1 += xr[k + 1] * __builtin_convertvector(w1, f32x4);
    }
    f32x4 acc = acc0 + acc1;
#pragma unroll
    for (int jj = 0; jj < 4; ++jj) {
      int c = cq * 4 + jj;
      float v = acc[jj];
      v = (v > 0.f) ? v : p.a2[c] * v;
      v = (v - p.m2[c]) * (1.f / sqrtf(p.v2[c] + 1e-3f)) * p.g2[c] + p.be2[c];
      x2[i * 68 + c] = v;
    }
  }
  for (int j = 0; j < 3; ++j) {            // stage W3 f16 (flat 1536)
    int u = tid + j * 512;
    if (u < 1536) W3h[u] = (_Float16)p.W3[u];
  }
  __syncthreads();

  if (tid < 384) {
    int i = tid & 15, c = tid >> 4;
    float acc = p.b3[c];
#pragma unroll 8
    for (int k = 0; k < 64; ++k) acc += x2[i * 68 + k] * (float)W3h[k * 24 + c];
    acc = (acc > 0.f) ? acc : p.a3[c] * acc;
    acc = (acc - p.m3[c]) * (1.f / sqrtf(p.v3[c] + 1e-3f)) * p.g3[c] + p.be3[c];
    x3[i * 28 + c] = acc;
  }
  __syncthreads();

  if (tid < BM) {
    float l0 = p.b4[0], l1 = p.b4[1];
#pragma unroll
    for (int k = 0; k < 24; ++k) {
      float v = x3[tid * 28 + k];
      l0 += v * p.W4[k * 2 + 0];
      l1 += v * p.W4[k * 2 + 1];
    }
    float m = fmaxf(l0, l1);
    float e0 = __expf(l0 - m), e1 = __expf(l1 - m);
    float inv = 1.f / (e0 + e1);
    p.out[(size_t)(m0 + tid) * 2 + 0] = e0 * inv;
    p.out[(size_t)(m0 + tid) * 2 + 1] = e1 * inv;
  }
}

extern "C" void kernel_launch(void* const* d_in, const int* in_sizes, int n_in,
                              void* d_out, int out_size, void* d_ws, size_t ws_size,
                              hipStream_t stream) {
  Params p;
  p.qid  = (const float*)d_in[0];
  p.node = (const float*)d_in[1];
  p.leaf = (const float*)d_in[2];
  p.pos_idx = (const int*)d_in[3];
  p.neg_idx = (const int*)d_in[4];
  p.p_leaf  = (const int*)d_in[5];
  p.n_leaf  = (const int*)d_in[6];
  p.W00 = (const float*)d_in[7];
  p.b00 = (const float*)d_in[8];
  p.a00 = (const float*)d_in[9];
  p.W01 = (const float*)d_in[10];
  p.b01 = (const float*)d_in[11];
  p.W1  = (const float*)d_in[12];
  p.b1  = (const float*)d_in[13];
  p.a1  = (const float*)d_in[14];
  p.g1  = (const float*)d_in[15];
  p.be1 = (const float*)d_in[16];
  p.m1  = (const float*)d_in[17];
  p.v1  = (const float*)d_in[18];
  p.W2  = (const float*)d_in[19];
  p.b2  = (const float*)d_in[20];
  p.a2  = (const float*)d_in[21];
  p.g2  = (const float*)d_in[22];
  p.be2 = (const float*)d_in[23];
  p.m2  = (const float*)d_in[24];
  p.v2  = (const float*)d_in[25];
  p.W3  = (const float*)d_in[26];
  p.b3  = (const float*)d_in[27];
  p.a3  = (const float*)d_in[28];
  p.g3  = (const float*)d_in[29];
  p.be3 = (const float*)d_in[30];
  p.m3  = (const float*)d_in[31];
  p.v3  = (const float*)d_in[32];
  p.W4  = (const float*)d_in[33];
  p.b4  = (const float*)d_in[34];
  p.Wp  = (_Float16*)d_ws;
  p.out = (float*)d_out;

  int B = in_sizes[3];              // 4096
  void* args[] = { (void*)&p };
  hipLaunchCooperativeKernel((const void*)fused, dim3(B / BM), dim3(512),
                             args, 0, stream);
}

// Round 10
// 58.104 us; speedup vs baseline: 2.2797x; 2.2797x over previous
//
#include <hip/hip_runtime.h>
#include <hip/hip_bf16.h>

typedef _Float16 half8 __attribute__((ext_vector_type(8)));
typedef _Float16 half4v __attribute__((ext_vector_type(4)));
typedef float f32x4 __attribute__((ext_vector_type(4)));

#define NCOLS 176               // 48 (padded 36-group) + 128
#define TILE_ELEMS (NCOLS*32)   // 5632 f16 per K-step tile
#define TILE_U16 (TILE_ELEMS/8) // 704 uint4 units
#define WTSTR 40                // pack LDS pad
#define XSTR2 2312              // f16 per X row: 2304 + 8 pad
#define BM 16
#define TICKET_OFF 851968       // ws offset of 72 ticket words (after Wp 811008)
#define MAGIC 0x5AFEC0DEu

// ---- LDS layout (bytes) ----
// GEMM phase: X @0 = 16*2312*2 = 73984
// Pack scratch T @73984 (disjoint from X -- R8 lesson)
// Tail aliases X only after X is dead:
#define OFF_A36 0        // [16][40] f32  = 2560
#define OFF_TQ  2560     // [16][128] f32 = 8192
#define OFF_TPN 10752    // [16][128] f32 = 8192
#define OFF_WV  18944    // [16] f32 pad64
#define OFF_X1  19008    // [16][132] f32 = 8448
#define OFF_W2  27456    // [128][64] f16 = 16384
#define OFF_X2  43840    // [16][68] f32  = 4352
#define OFF_W3  48192    // [64][24] f16  = 3072
#define OFF_X3  51264    // [16][28] f32  = 1792 -> 53056
#define OFF_SCR 53056    // K reduce scratch (post-X-death): 24576 -> 77632
#define OFF_T   73984    // pack scratch (disjoint from live X)
#define SM_BYTES 88064

struct Params {
  const float *qid, *node, *leaf;
  const int *pos_idx, *neg_idx, *p_leaf, *n_leaf;
  const float *W00, *W1;
  const float *b00, *a00, *W01, *b01;
  const float *b1, *a1, *g1, *be1, *m1, *v1;
  const float *W2, *b2, *a2, *g2, *be2, *m2, *v2;
  const float *W3, *b3, *a3, *g3, *be3, *m3, *v3;
  const float *W4, *b4;
  _Float16 *Wp;          // ws + 0: 72*5632*2 = 811008 B
  unsigned *tickets;     // ws + TICKET_OFF: 72 words
  float *out;
};

// ONE regular dispatch, 256 blocks x 512 threads (1 block/CU -> co-resident).
// Blocks 0..71: pack Wp tile, fence, release ticket. All blocks: issue all
// gathers + stage X (hides under pack window), acquire-spin on 72 tickets,
// one barrier, then R4's barrier-free K-loop + reduction + fused tail.
__global__ __launch_bounds__(512) void fused(Params p) {
  __shared__ __align__(16) char sm[SM_BYTES];

  _Float16* X   = (_Float16*)sm;
  float*    A36 = (float*)(sm + OFF_A36);
  float*    Tq  = (float*)(sm + OFF_TQ);
  float*    Tpn = (float*)(sm + OFF_TPN);
  float*    wv  = (float*)(sm + OFF_WV);
  float*    x1  = (float*)(sm + OFF_X1);
  _Float16* W2h = (_Float16*)(sm + OFF_W2);
  float*    x2  = (float*)(sm + OFF_X2);
  _Float16* W3h = (_Float16*)(sm + OFF_W3);
  float*    x3  = (float*)(sm + OFF_X3);
  float*    scr = (float*)(sm + OFF_SCR);
  _Float16* T   = (_Float16*)(sm + OFF_T);

  const int tid  = threadIdx.x;
  const int wid  = tid >> 6;
  const int lane = tid & 63;
  const int lm   = lane & 15;
  const int hk   = lane >> 4;
  const int nw   = wid & 3;
  const int kg   = wid >> 2;              // 0/1 K parity
  const int m0   = blockIdx.x * BM;
  const bool HAS2 = (nw < 3);

  // ---- producer: blocks 0..71 pack their Wp tile FIRST ----
  if (blockIdx.x < 72) {
    int g = blockIdx.x;
    int s = g / 24, t = g - s * 24;
    int k0 = t * 32;
    int w1row0 = (s == 0) ? 1536 : (s == 1 ? 0 : 768);
    for (int u = tid; u < 1024; u += 512) {          // W1 part
      int kk = u >> 5, c4 = u & 31;
      float4 f = *(const float4*)(p.W1 + (size_t)(w1row0 + k0 + kk) * 128 + c4 * 4);
      int c = 48 + c4 * 4;
      T[(c + 0) * WTSTR + kk] = (_Float16)f.x; T[(c + 1) * WTSTR + kk] = (_Float16)f.y;
      T[(c + 2) * WTSTR + kk] = (_Float16)f.z; T[(c + 3) * WTSTR + kk] = (_Float16)f.w;
    }
    for (int u = tid; u < 1152; u += 512) {          // W00 part
      int kk = u / 36, c = u - kk * 36;
      T[c * WTSTR + kk] = (_Float16)p.W00[(size_t)(s * 768 + k0 + kk) * 36 + c];
    }
    for (int u = tid; u < 384; u += 512) {           // zero pad cols 36..47
      int kk = u & 31, c = 36 + (u >> 5);
      T[c * WTSTR + kk] = (_Float16)0.f;
    }
    __syncthreads();
    uint4* dst = (uint4*)(p.Wp + (size_t)g * TILE_ELEMS);
    for (int u = tid; u < TILE_U16; u += 512) {
      int c = u >> 2, q = u & 3;
      dst[u] = *(const uint4*)&T[c * WTSTR + q * 8];
    }
    __threadfence();                       // per-thread agent-scope writeback
    __syncthreads();                       // all threads' stores drained
    if (tid == 0)
      __hip_atomic_store(&p.tickets[g], MAGIC, __ATOMIC_RELEASE,
                         __HIP_MEMORY_SCOPE_AGENT);
  }

  // ---- all blocks: issue all gathers, stage X (overlaps pack window) ----
  auto rowbase = [&](int s, int i) -> const float* {
    if (s == 0) return p.qid + (size_t)(m0 + i) * 768;
    int idx = (s == 1 ? p.pos_idx : p.neg_idx)[m0 + i];
    int lf  = (s == 1 ? p.p_leaf  : p.n_leaf )[m0 + i];
    return ((lf == 1) ? p.leaf : p.node) + (size_t)idx * 768;
  };
  float4 sA[6], sB[6], sC[6];
  auto stageLoad = [&](int s, float4* sr) {
#pragma unroll
    for (int jj = 0; jj < 6; ++jj) {
      int v = tid + jj * 512;             // < 3072 = 16 rows * 192 float4
      int i = v / 192, c4 = v - i * 192;
      sr[jj] = ((const float4*)rowbase(s, i))[c4];
    }
  };
  auto stageWrite = [&](int s, const float4* sr) {
#pragma unroll
    for (int jj = 0; jj < 6; ++jj) {
      int v = tid + jj * 512;
      int i = v / 192, c4 = v - i * 192;
      float4 f = sr[jj];
      half4v h = { (_Float16)f.x, (_Float16)f.y, (_Float16)f.z, (_Float16)f.w };
      *(half4v*)(X + i * XSTR2 + s * 768 + c4 * 4) = h;
    }
  };

  stageLoad(0, sA);
  stageLoad(1, sB);
  stageLoad(2, sC);
  stageWrite(0, sA);
  stageWrite(1, sB);
  stageWrite(2, sC);

  // ---- gate: wait for all 72 Wp tiles (acquire invalidates stale L2) ----
  if (tid < 72) {
    while (__hip_atomic_load(&p.tickets[tid], __ATOMIC_ACQUIRE,
                             __HIP_MEMORY_SCOPE_AGENT) != MAGIC)
      __builtin_amdgcn_s_sleep(4);
  }
  __syncthreads();                         // X published + gate passed

  // ---- barrier-free K-loop (R4-proven) ----
  const uint4* Wp4 = (const uint4*)p.Wp;
  const int woff = ((nw * 48 + lm) << 2) + hk;

  uint4 P[4][3];
  auto ldWp = [&](int t) {                 // tile g = kg + 2t
    const uint4* b = Wp4 + (size_t)(kg + 2 * t) * TILE_U16 + woff;
    P[t & 3][0] = b[0]; P[t & 3][1] = b[64];
    if (HAS2) P[t & 3][2] = b[128];
  };
  auto ldA = [&](int t) -> half8 {
    return *(const half8*)(X + lm * XSTR2 + (kg + 2 * t) * 32 + hk * 8);
  };

  f32x4 accA[3] = {{0.f,0.f,0.f,0.f},{0.f,0.f,0.f,0.f},{0.f,0.f,0.f,0.f}};
  f32x4 accB[3] = {{0.f,0.f,0.f,0.f},{0.f,0.f,0.f,0.f},{0.f,0.f,0.f,0.f}};
  half8 av[3];

  ldWp(0); ldWp(1); ldWp(2); ldWp(3);
  av[0] = ldA(0); av[1] = ldA(1); av[2] = ldA(2);

#pragma unroll
  for (int t = 0; t < 36; ++t) {
    half8 a  = av[t % 3];
    half8 b0 = __builtin_bit_cast(half8, P[t & 3][0]);
    half8 b1 = __builtin_bit_cast(half8, P[t & 3][1]);
    half8 b2 = __builtin_bit_cast(half8, P[t & 3][2]);
    if ((nw == 0) || (t < 12)) {
      accA[0] = __builtin_amdgcn_mfma_f32_16x16x32_f16(a, b0, accA[0], 0, 0, 0);
      accA[1] = __builtin_amdgcn_mfma_f32_16x16x32_f16(a, b1, accA[1], 0, 0, 0);
      if (HAS2) accA[2] = __builtin_amdgcn_mfma_f32_16x16x32_f16(a, b2, accA[2], 0, 0, 0);
    } else {
      accB[0] = __builtin_amdgcn_mfma_f32_16x16x32_f16(a, b0, accB[0], 0, 0, 0);
      accB[1] = __builtin_amdgcn_mfma_f32_16x16x32_f16(a, b1, accB[1], 0, 0, 0);
      if (HAS2) accB[2] = __builtin_amdgcn_mfma_f32_16x16x32_f16(a, b2, accB[2], 0, 0, 0);
    }
    if (t + 4 < 36) ldWp(t + 4);
    if (t + 3 < 36) av[t % 3] = ldA(t + 3);
  }

  // issue tail W2 loads (land during reduction)
  float4 w2r[4];
#pragma unroll
  for (int jj = 0; jj < 4; ++jj) w2r[jj] = ((const float4*)p.W2)[tid + jj * 512];

  // ---- kg-parity reduction (scr aliases X; X dead after this barrier) ----
  __syncthreads();
  if (kg == 1) {
#pragma unroll
    for (int n = 0; n < 3; ++n) {
      if (n < 2 || HAS2) {
#pragma unroll
        for (int r = 0; r < 4; ++r) {
          int base = ((nw * 3 + n) * 2) * 256 + (hk * 4 + r) * 16 + lm;
          scr[base]       = accA[n][r];
          scr[base + 256] = accB[n][r];
        }
      }
    }
  }
  __syncthreads();
  if (kg == 0) {
#pragma unroll
    for (int n = 0; n < 3; ++n) {
      if (n < 2 || HAS2) {
#pragma unroll
        for (int r = 0; r < 4; ++r) {
          int base = ((nw * 3 + n) * 2) * 256 + (hk * 4 + r) * 16 + lm;
          float va = accA[n][r] + scr[base];
          float vb = accB[n][r] + scr[base + 256];
          int row = hk * 4 + r;
          int col = nw * 48 + n * 16 + lm;
          if (nw == 0) { if (col < 36) A36[row * 40 + col] = va; }
          else { int rc = col - 48; Tq[row * 128 + rc] = va; Tpn[row * 128 + rc] = vb; }
        }
      }
    }
  }
  __syncthreads();

  // ---- fused tail (R4-verified) ----
#pragma unroll
  for (int jj = 0; jj < 4; ++jj) {
    int u = tid + jj * 512;                // 2048 float4 = 128*64/4
    float4 f = w2r[jj];
    half4v h = { (_Float16)f.x, (_Float16)f.y, (_Float16)f.z, (_Float16)f.w };
    *(half4v*)(W2h + (u >> 4) * 64 + (u & 15) * 4) = h;
  }
  if (tid < BM) {
    float acc = p.b01[0];
    for (int c = 0; c < 36; ++c) {
      float h = A36[tid * 40 + c] + p.b00[c];
      h = (h > 0.f) ? h : p.a00[c] * h;
      acc += h * p.W01[c];
    }
    wv[tid] = acc;
  }
  __syncthreads();

#pragma unroll
  for (int j = 0; j < 4; ++j) {
    int u = tid + j * 512;                 // 2048 = 16*128
    int i = u >> 7, c = u & 127;
    float v = wv[i] * Tpn[i * 128 + c] + Tq[i * 128 + c] + p.b1[c];
    v = (v > 0.f) ? v : p.a1[c] * v;
    v = (v - p.m1[c]) * (1.f / sqrtf(p.v1[c] + 1e-3f)) * p.g1[c] + p.be1[c];
    x1[i * 132 + c] = v;
  }
  __syncthreads();

  if (tid < 256) {
    int i = tid & 15, cq = tid >> 4;
    const float* xr = x1 + i * 132;
    f32x4 acc0 = { p.b2[cq*4+0], p.b2[cq*4+1], p.b2[cq*4+2], p.b2[cq*4+3] };
    f32x4 acc1 = { 0.f, 0.f, 0.f, 0.f };
#pragma unroll 8
    for (int k = 0; k < 128; k += 2) {
      half4v w0 = *(const half4v*)(W2h + k * 64 + cq * 4);
      half4v w1 = *(const half4v*)(W2h + (k + 1) * 64 + cq * 4);
      acc0 += xr[k]     * __builtin_convertvector(w0, f32x4);
      acc1 += xr[k + 1] * __builtin_convertvector(w1, f32x4);
    }
    f32x4 acc = acc0 + acc1;
#pragma unroll
    for (int jj = 0; jj < 4; ++jj) {
      int c = cq * 4 + jj;
      float v = acc[jj];
      v = (v > 0.f) ? v : p.a2[c] * v;
      v = (v - p.m2[c]) * (1.f / sqrtf(p.v2[c] + 1e-3f)) * p.g2[c] + p.be2[c];
      x2[i * 68 + c] = v;
    }
  }
  for (int j = 0; j < 3; ++j) {            // stage W3 f16 (flat 1536)
    int u = tid + j * 512;
    if (u < 1536) W3h[u] = (_Float16)p.W3[u];
  }
  __syncthreads();

  if (tid < 384) {
    int i = tid & 15, c = tid >> 4;
    float acc = p.b3[c];
#pragma unroll 8
    for (int k = 0; k < 64; ++k) acc += x2[i * 68 + k] * (float)W3h[k * 24 + c];
    acc = (acc > 0.f) ? acc : p.a3[c] * acc;
    acc = (acc - p.m3[c]) * (1.f / sqrtf(p.v3[c] + 1e-3f)) * p.g3[c] + p.be3[c];
    x3[i * 28 + c] = acc;
  }
  __syncthreads();

  if (tid < BM) {
    float l0 = p.b4[0], l1 = p.b4[1];
#pragma unroll
    for (int k = 0; k < 24; ++k) {
      float v = x3[tid * 28 + k];
      l0 += v * p.W4[k * 2 + 0];
      l1 += v * p.W4[k * 2 + 1];
    }
    float m = fmaxf(l0, l1);
    float e0 = __expf(l0 - m), e1 = __expf(l1 - m);
    float inv = 1.f / (e0 + e1);
    p.out[(size_t)(m0 + tid) * 2 + 0] = e0 * inv;
    p.out[(size_t)(m0 + tid) * 2 + 1] = e1 * inv;
  }
}

extern "C" void kernel_launch(void* const* d_in, const int* in_sizes, int n_in,
                              void* d_out, int out_size, void* d_ws, size_t ws_size,
                              hipStream_t stream) {
  Params p;
  p.qid  = (const float*)d_in[0];
  p.node = (const float*)d_in[1];
  p.leaf = (const float*)d_in[2];
  p.pos_idx = (const int*)d_in[3];
  p.neg_idx = (const int*)d_in[4];
  p.p_leaf  = (const int*)d_in[5];
  p.n_leaf  = (const int*)d_in[6];
  p.W00 = (const float*)d_in[7];
  p.b00 = (const float*)d_in[8];
  p.a00 = (const float*)d_in[9];
  p.W01 = (const float*)d_in[10];
  p.b01 = (const float*)d_in[11];
  p.W1  = (const float*)d_in[12];
  p.b1  = (const float*)d_in[13];
  p.a1  = (const float*)d_in[14];
  p.g1  = (const float*)d_in[15];
  p.be1 = (const float*)d_in[16];
  p.m1  = (const float*)d_in[17];
  p.v1  = (const float*)d_in[18];
  p.W2  = (const float*)d_in[19];
  p.b2  = (const float*)d_in[20];
  p.a2  = (const float*)d_in[21];
  p.g2  = (const float*)d_in[22];
  p.be2 = (const float*)d_in[23];
  p.m2  = (const float*)d_in[24];
  p.v2  = (const float*)d_in[25];
  p.W3  = (const float*)d_in[26];
  p.b3  = (const float*)d_in[27];
  p.a3  = (const float*)d_in[28];
  p.g3  = (const float*)d_in[29];
  p.be3 = (const float*)d_in[30];
  p.m3  = (const float*)d_in[31];
  p.v3  = (const float*)d_in[32];
  p.W4  = (const float*)d_in[33];
  p.b4  = (const float*)d_in[34];
  p.Wp  = (_Float16*)d_ws;
  p.tickets = (unsigned*)((char*)d_ws + TICKET_OFF);
  p.out = (float*)d_out;

  int B = in_sizes[3];              // 4096
  fused<<<B / BM, 512, 0, stream>>>(p);
}

// Round 11
// 38.127 us; speedup vs baseline: 3.4742x; 1.5239x over previous
//
#include <hip/hip_runtime.h>
#include <hip/hip_bf16.h>

typedef _Float16 half8 __attribute__((ext_vector_type(8)));
typedef _Float16 half4v __attribute__((ext_vector_type(4)));
typedef float f32x4 __attribute__((ext_vector_type(4)));

#define NCOLS 176               // 48 (padded 36-group) + 128
#define TILE_ELEMS (NCOLS*32)   // 5632 f16 per K-step tile
#define TILE_U16 (TILE_ELEMS/8) // 704 uint4 units
#define XSTR2 2312              // f16 per X row: 2304 + 8 pad
#define BM 16

// ---- fused_main shared memory layout (bytes) ----
// GEMM phase: X @0 = 16*2312*2 = 73984
// Tail phase (aliases X region, used only after X dead):
#define OFF_A36 0        // [16][40] f32  = 2560
#define OFF_TQ  2560     // [16][128] f32 = 8192
#define OFF_TPN 10752    // [16][128] f32 = 8192
#define OFF_WV  18944    // [16] f32      = 64
#define OFF_X1  19008    // [16][132] f32 = 8448
#define OFF_W2  27456    // [128][64] f16 = 16384
#define OFF_X2  43840    // [16][68] f32  = 4352
#define OFF_W3  48192    // [64][24] f16  = 3072
#define OFF_X3  51264    // [16][28] f32  = 1792 -> 53056
#define OFF_SCR 53056    // K-parity reduce scratch [12][2][256] f32 = 24576
#define SM_BYTES 77632

struct Params {
  const float *qid, *node, *leaf;
  const int *pos_idx, *neg_idx, *p_leaf, *n_leaf;
  const float *b00, *a00, *W01, *b01;
  const float *b1, *a1, *g1, *be1, *m1, *v1;
  const float *W2, *b2, *a2, *g2, *be2, *m2, *v2;
  const float *W3, *b3, *a3, *g3, *be3, *m3, *v3;
  const float *W4, *b4;
  const _Float16 *Wp;
  float *out;
};

// K0: pack weights -> f16, layout [g = s*24+t][col 0..175][k 0..31].
// 144 blocks: block b packs half-tile (g = b>>1, k-half = b&1) -> half the
// per-block work of the 72-block version, ~halving pack wall time.
__global__ __launch_bounds__(256) void pack_weights(const float* __restrict__ W00,
                                                    const float* __restrict__ W1,
                                                    _Float16* __restrict__ Wp) {
  int b = blockIdx.x;              // 0..143
  int g = b >> 1;                  // tile 0..71
  int half = b & 1;                // k-half: 0 -> k 0..15, 1 -> k 16..31
  int s = g / 24, t = g - s * 24;
  int k0 = t * 32 + half * 16;
  int w1row0 = (s == 0) ? 1536 : (s == 1 ? 0 : 768);
  __shared__ _Float16 T[NCOLS][24];          // 16 k + 8 pad
  int tid = threadIdx.x;
  for (int u = tid; u < 512; u += 256) {     // W1 part: 16 kk x 32 float4
    int kk = u >> 5, c4 = u & 31;
    float4 f = *(const float4*)(W1 + (size_t)(w1row0 + k0 + kk) * 128 + c4 * 4);
    int c = 48 + c4 * 4;
    T[c + 0][kk] = (_Float16)f.x; T[c + 1][kk] = (_Float16)f.y;
    T[c + 2][kk] = (_Float16)f.z; T[c + 3][kk] = (_Float16)f.w;
  }
  for (int u = tid; u < 576; u += 256) {     // W00 part: 16 kk x 36 c
    int kk = u / 36, c = u - kk * 36;
    T[c][kk] = (_Float16)W00[(size_t)(s * 768 + k0 + kk) * 36 + c];
  }
  for (int u = tid; u < 192; u += 256) {     // zero pad cols 36..47
    int kk = u & 15, c = 36 + (u >> 4);
    T[c][kk] = (_Float16)0.f;
  }
  __syncthreads();
  uint4* dst = (uint4*)(Wp + (size_t)g * TILE_ELEMS);
  for (int u = tid; u < 352; u += 256) {     // 176 cols x 2 uint4 (this k-half)
    int c = u >> 1, q = u & 1;
    dst[c * 4 + half * 2 + q] = *(const uint4*)&T[c][q * 8];
  }
}

// 512 threads = 8 waves: nw = wid&3 -> col group, kg = wid>>2 -> K-tile parity.
// Segment-pipelined (R4-champion): stage seg s+1 while K-loop runs on seg s;
// write-late + one barrier per segment. W stream: global->reg 4-deep from L2.
__global__ __launch_bounds__(512) void fused_main(Params p) {
  __shared__ __align__(16) char sm[SM_BYTES];
  __shared__ const float* Xbase[3][BM];

  _Float16* X   = (_Float16*)sm;
  float*    A36 = (float*)(sm + OFF_A36);
  float*    Tq  = (float*)(sm + OFF_TQ);
  float*    Tpn = (float*)(sm + OFF_TPN);
  float*    wv  = (float*)(sm + OFF_WV);
  float*    x1  = (float*)(sm + OFF_X1);
  _Float16* W2h = (_Float16*)(sm + OFF_W2);
  float*    x2  = (float*)(sm + OFF_X2);
  _Float16* W3h = (_Float16*)(sm + OFF_W3);
  float*    x3  = (float*)(sm + OFF_X3);
  float*    scr = (float*)(sm + OFF_SCR);

  const int tid  = threadIdx.x;
  const int wid  = tid >> 6;
  const int lane = tid & 63;
  const int lm   = lane & 15;
  const int hk   = lane >> 4;
  const int nw   = wid & 3;
  const int kg   = wid >> 2;
  const int m0   = blockIdx.x * BM;
  const bool HAS2 = (nw < 3);

  const uint4* Wp4 = (const uint4*)p.Wp;
  const int woff = ((nw * 48 + lm) << 2) + hk;

  uint4 P[4][3];
  auto ldWp = [&](int j) {                 // j = wave-sequence index 0..35
    int s = j / 12;
    int g = s * 24 + kg + 2 * (j - s * 12);
    const uint4* b = Wp4 + (size_t)g * TILE_U16 + woff;
    P[j & 3][0] = b[0]; P[j & 3][1] = b[64];
    if (HAS2) P[j & 3][2] = b[128];
  };

  // ---- prologue: W prefetch + gather resolve + seg0 loads, all in flight ----
  ldWp(0); ldWp(1); ldWp(2); ldWp(3);

  if (tid < 3 * BM) {
    int s = tid >> 4, i = tid & 15;
    const float* base;
    if (s == 0) base = p.qid + (size_t)(m0 + i) * 768;
    else if (s == 1) {
      int idx = p.pos_idx[m0 + i];
      base = ((p.p_leaf[m0 + i] == 1) ? p.leaf : p.node) + (size_t)idx * 768;
    } else {
      int idx = p.neg_idx[m0 + i];
      base = ((p.n_leaf[m0 + i] == 1) ? p.leaf : p.node) + (size_t)idx * 768;
    }
    Xbase[s][i] = base;
  }

  float4 sregA[6], sregB[6];
  auto stageLoad = [&](int s, float4* sr) {
#pragma unroll
    for (int jj = 0; jj < 6; ++jj) {
      int v = tid + jj * 512;             // < 3072 = 16 rows * 192 float4
      int i = v / 192, c4 = v - i * 192;
      const float* b = (s == 0) ? (p.qid + (size_t)(m0 + i) * 768) : Xbase[s][i];
      sr[jj] = ((const float4*)b)[c4];
    }
  };
  auto stageWrite = [&](int s, const float4* sr) {
#pragma unroll
    for (int jj = 0; jj < 6; ++jj) {
      int v = tid + jj * 512;
      int i = v / 192, c4 = v - i * 192;
      float4 f = sr[jj];
      half4v h = { (_Float16)f.x, (_Float16)f.y, (_Float16)f.z, (_Float16)f.w };
      *(half4v*)(X + i * XSTR2 + s * 768 + c4 * 4) = h;
    }
  };

  stageLoad(0, sregA);                     // q: direct addresses, no barrier needed
  __syncthreads();                         // Xbase visible
  stageLoad(1, sregB);                     // pos gather: issued before seg0 write
  stageWrite(0, sregA);
  __syncthreads();                         // seg0 staged

  // ---- K-loop over 3 segments, 12 tiles/wave each ----
  f32x4 accA[3] = {{0.f,0.f,0.f,0.f},{0.f,0.f,0.f,0.f},{0.f,0.f,0.f,0.f}};
  f32x4 accB[3] = {{0.f,0.f,0.f,0.f},{0.f,0.f,0.f,0.f},{0.f,0.f,0.f,0.f}};
  half8 av[3];

  auto ldA = [&](int g) -> half8 {
    return *(const half8*)(X + lm * XSTR2 + g * 32 + hk * 8);
  };
  auto comp = [&](int g, int slot, half8 a) {
    half8 b0 = __builtin_bit_cast(half8, P[slot][0]);
    half8 b1 = __builtin_bit_cast(half8, P[slot][1]);
    half8 b2 = __builtin_bit_cast(half8, P[slot][2]);
    if ((nw == 0) || (g < 24)) {
      accA[0] = __builtin_amdgcn_mfma_f32_16x16x32_f16(a, b0, accA[0], 0, 0, 0);
      accA[1] = __builtin_amdgcn_mfma_f32_16x16x32_f16(a, b1, accA[1], 0, 0, 0);
      if (HAS2) accA[2] = __builtin_amdgcn_mfma_f32_16x16x32_f16(a, b2, accA[2], 0, 0, 0);
    } else {
      accB[0] = __builtin_amdgcn_mfma_f32_16x16x32_f16(a, b0, accB[0], 0, 0, 0);
      accB[1] = __builtin_amdgcn_mfma_f32_16x16x32_f16(a, b1, accB[1], 0, 0, 0);
      if (HAS2) accB[2] = __builtin_amdgcn_mfma_f32_16x16x32_f16(a, b2, accB[2], 0, 0, 0);
    }
  };

  float4 w2r[4];
#pragma unroll
  for (int s = 0; s < 3; ++s) {
    if (s == 1) {                          // issue tail W2 loads; publish pos
#pragma unroll
      for (int jj = 0; jj < 4; ++jj) w2r[jj] = ((const float4*)p.W2)[tid + jj * 512];
      stageLoad(2, sregA);
      stageWrite(1, sregB);
      __syncthreads();
    }
    if (s == 2) {                          // publish neg
      stageWrite(2, sregA);
      __syncthreads();
    }
    const int gb = s * 24 + kg;
    av[0] = ldA(gb); av[1] = ldA(gb + 2); av[2] = ldA(gb + 4);
#pragma unroll
    for (int tt = 0; tt < 12; ++tt) {
      int j = s * 12 + tt;
      comp(gb + 2 * tt, j & 3, av[tt % 3]);
      if (j + 4 < 36) ldWp(j + 4);
      if (tt + 3 < 12) av[tt % 3] = ldA(gb + 2 * (tt + 3));
    }
  }

  // ---- K-parity reduction ----
  __syncthreads();                         // all X reads done
  if (kg == 1) {
#pragma unroll
    for (int n = 0; n < 3; ++n) {
      if (n < 2 || HAS2) {
#pragma unroll
        for (int r = 0; r < 4; ++r) {
          int base = ((nw * 3 + n) * 2) * 256 + (hk * 4 + r) * 16 + lm;
          scr[base]       = accA[n][r];
          scr[base + 256] = accB[n][r];
        }
      }
    }
  }
  __syncthreads();
  if (kg == 0) {
#pragma unroll
    for (int n = 0; n < 3; ++n) {
      if (n < 2 || HAS2) {
#pragma unroll
        for (int r = 0; r < 4; ++r) {
          int base = ((nw * 3 + n) * 2) * 256 + (hk * 4 + r) * 16 + lm;
          float va = accA[n][r] + scr[base];
          float vb = accB[n][r] + scr[base + 256];
          int row = hk * 4 + r;
          int col = nw * 48 + n * 16 + lm;
          if (nw == 0) { if (col < 36) A36[row * 40 + col] = va; }
          else { int rc = col - 48; Tq[row * 128 + rc] = va; Tpn[row * 128 + rc] = vb; }
        }
      }
    }
  }
  __syncthreads();

  // ---- fused tail ----
  // write-late W2 (loads issued at seg1 start) + per-sample scalar w
#pragma unroll
  for (int jj = 0; jj < 4; ++jj) {
    int u = tid + jj * 512;                // 2048 float4 units = 128*64/4
    float4 f = w2r[jj];
    half4v h = { (_Float16)f.x, (_Float16)f.y, (_Float16)f.z, (_Float16)f.w };
    *(half4v*)(W2h + (u >> 4) * 64 + (u & 15) * 4) = h;
  }
  if (tid < BM) {
    float acc = p.b01[0];
    for (int c = 0; c < 36; ++c) {
      float h = A36[tid * 40 + c] + p.b00[c];
      h = (h > 0.f) ? h : p.a00[c] * h;
      acc += h * p.W01[c];
    }
    wv[tid] = acc;
  }
  __syncthreads();

  // x1 = bn1(prelu(w*Tpn + Tq + b1)): 16*128 = 2048 elems
#pragma unroll
  for (int j = 0; j < 4; ++j) {
    int u = tid + j * 512;
    int i = u >> 7, c = u & 127;
    float v = wv[i] * Tpn[i * 128 + c] + Tq[i * 128 + c] + p.b1[c];
    v = (v > 0.f) ? v : p.a1[c] * v;
    v = (v - p.m1[c]) * (1.f / sqrtf(p.v1[c] + 1e-3f)) * p.g1[c] + p.be1[c];
    x1[i * 132 + c] = v;
  }
  __syncthreads();

  // x2 = bn2(prelu(x1 @ W2 + b2)); threads 0..255: one per (sample, 4-col group)
  if (tid < 256) {
    int i = tid & 15, cq = tid >> 4;
    const float* xr = x1 + i * 132;
    f32x4 acc0 = { p.b2[cq*4+0], p.b2[cq*4+1], p.b2[cq*4+2], p.b2[cq*4+3] };
    f32x4 acc1 = { 0.f, 0.f, 0.f, 0.f };
#pragma unroll 8
    for (int k = 0; k < 128; k += 2) {
      half4v w0 = *(const half4v*)(W2h + k * 64 + cq * 4);
      half4v w1 = *(const half4v*)(W2h + (k + 1) * 64 + cq * 4);
      acc0 += xr[k]     * __builtin_convertvector(w0, f32x4);
      acc1 += xr[k + 1] * __builtin_convertvector(w1, f32x4);
    }
    f32x4 acc = acc0 + acc1;
#pragma unroll
    for (int jj = 0; jj < 4; ++jj) {
      int c = cq * 4 + jj;
      float v = acc[jj];
      v = (v > 0.f) ? v : p.a2[c] * v;
      v = (v - p.m2[c]) * (1.f / sqrtf(p.v2[c] + 1e-3f)) * p.g2[c] + p.be2[c];
      x2[i * 68 + c] = v;
    }
  }
  for (int j = 0; j < 3; ++j) {           // stage W3 as f16 (flat 1536)
    int u = tid + j * 512;
    if (u < 1536) W3h[u] = (_Float16)p.W3[u];
  }
  __syncthreads();

  // x3 = bn3(prelu(x2 @ W3 + b3)): 16*24 = 384 outputs
  if (tid < 384) {
    int i = tid & 15, c = tid >> 4;
    float acc = p.b3[c];
#pragma unroll 8
    for (int k = 0; k < 64; ++k) acc += x2[i * 68 + k] * (float)W3h[k * 24 + c];
    acc = (acc > 0.f) ? acc : p.a3[c] * acc;
    acc = (acc - p.m3[c]) * (1.f / sqrtf(p.v3[c] + 1e-3f)) * p.g3[c] + p.be3[c];
    x3[i * 28 + c] = acc;
  }
  __syncthreads();

  // logits + softmax
  if (tid < BM) {
    float l0 = p.b4[0], l1 = p.b4[1];
#pragma unroll
    for (int k = 0; k < 24; ++k) {
      float v = x3[tid * 28 + k];
      l0 += v * p.W4[k * 2 + 0];
      l1 += v * p.W4[k * 2 + 1];
    }
    float m = fmaxf(l0, l1);
    float e0 = __expf(l0 - m), e1 = __expf(l1 - m);
    float inv = 1.f / (e0 + e1);
    p.out[(size_t)(m0 + tid) * 2 + 0] = e0 * inv;
    p.out[(size_t)(m0 + tid) * 2 + 1] = e1 * inv;
  }
}

extern "C" void kernel_launch(void* const* d_in, const int* in_sizes, int n_in,
                              void* d_out, int out_size, void* d_ws, size_t ws_size,
                              hipStream_t stream) {
  const float* qid  = (const float*)d_in[0];
  const float* node = (const float*)d_in[1];
  const float* leaf = (const float*)d_in[2];
  const int* positives = (const int*)d_in[3];
  const int* negetives = (const int*)d_in[4];
  const int* p_isleafs = (const int*)d_in[5];
  const int* n_isleafs = (const int*)d_in[6];
  const float* W00 = (const float*)d_in[7];
  const float* b00 = (const float*)d_in[8];
  const float* a00 = (const float*)d_in[9];
  const float* W01 = (const float*)d_in[10];
  const float* b01 = (const float*)d_in[11];
  const float* W1  = (const float*)d_in[12];
  const float* b1  = (const float*)d_in[13];
  const float* a1  = (const float*)d_in[14];
  const float* g1  = (const float*)d_in[15];
  const float* be1 = (const float*)d_in[16];
  const float* m1  = (const float*)d_in[17];
  const float* v1  = (const float*)d_in[18];
  const float* W2  = (const float*)d_in[19];
  const float* b2  = (const float*)d_in[20];
  const float* a2  = (const float*)d_in[21];
  const float* g2  = (const float*)d_in[22];
  const float* be2 = (const float*)d_in[23];
  const float* m2  = (const float*)d_in[24];
  const float* v2  = (const float*)d_in[25];
  const float* W3  = (const float*)d_in[26];
  const float* b3  = (const float*)d_in[27];
  const float* a3  = (const float*)d_in[28];
  const float* g3  = (const float*)d_in[29];
  const float* be3 = (const float*)d_in[30];
  const float* m3  = (const float*)d_in[31];
  const float* v3  = (const float*)d_in[32];
  const float* W4  = (const float*)d_in[33];
  const float* b4  = (const float*)d_in[34];

  _Float16* Wp = (_Float16*)d_ws;   // 72*5632*2 = 811008 bytes

  pack_weights<<<144, 256, 0, stream>>>(W00, W1, Wp);

  Params p;
  p.qid = qid; p.node = node; p.leaf = leaf;
  p.pos_idx = positives; p.neg_idx = negetives; p.p_leaf = p_isleafs; p.n_leaf = n_isleafs;
  p.b00 = b00; p.a00 = a00; p.W01 = W01; p.b01 = b01;
  p.b1 = b1; p.a1 = a1; p.g1 = g1; p.be1 = be1; p.m1 = m1; p.v1 = v1;
  p.W2 = W2; p.b2 = b2; p.a2 = a2; p.g2 = g2; p.be2 = be2; p.m2 = m2; p.v2 = v2;
  p.W3 = W3; p.b3 = b3; p.a3 = a3; p.g3 = g3; p.be3 = be3; p.m3 = m3; p.v3 = v3;
  p.W4 = W4; p.b4 = b4;
  p.Wp = Wp;
  p.out = (float*)d_out;

  int B = in_sizes[3];              // 4096
  fused_main<<<B / BM, 512, 0, stream>>>(p);
}